// Round 1
// baseline (156.909 us; speedup 1.0000x reference)
//
#include <hip/hip_runtime.h>

// ---------------------------------------------------------------------------
// attention_76089640615954 on MI355X (gfx950)
// x:[1,256,64,64] -> 1x1 conv (3C) -> 11x11 depthwise -> 8-head attn (N=4096,
// d=32, temp=5) -> 1x1 conv + bias -> relu + residual.
// Strategy: fp16 MFMA (16x16x32) for all GEMM-shaped work, fp32 accumulate.
// ---------------------------------------------------------------------------

typedef _Float16 f16;
typedef _Float16 f16x8 __attribute__((ext_vector_type(8)));
typedef float f32x4 __attribute__((ext_vector_type(4)));

#define HW 4096      // 64*64 pixels
#define NC 256       // channels

static __device__ __forceinline__ f32x4 mfma16(f16x8 a, f16x8 b, f32x4 c) {
  return __builtin_amdgcn_mfma_f32_16x16x32_f16(a, b, c, 0, 0, 0);
}

// --------------------------- prep: weights -> fp16 -------------------------
__global__ __launch_bounds__(256) void k_prep_w(
    const float* __restrict__ wpw, const float* __restrict__ wlin,
    f16* __restrict__ wpw_h, f16* __restrict__ wlin_h) {
  int i = blockIdx.x * 256 + threadIdx.x;
  int stride = gridDim.x * 256;
  for (int idx = i; idx < 3 * NC * NC; idx += stride) wpw_h[idx] = (f16)wpw[idx];
  for (int idx = i; idx < NC * NC; idx += stride) wlin_h[idx] = (f16)wlin[idx];
}

// --------------------------- prep: x -> xt[p][c] fp16 ----------------------
__global__ __launch_bounds__(256) void k_transpose_x(
    const float* __restrict__ x, f16* __restrict__ xt) {
  __shared__ float t[32][33];
  int bc = blockIdx.x >> 7;    // 8 channel tiles of 32
  int bp = blockIdx.x & 127;   // 128 pixel tiles of 32
  int tx = threadIdx.x & 31, ty = threadIdx.x >> 5;  // ty 0..7
#pragma unroll
  for (int i = 0; i < 4; i++) {
    int c = bc * 32 + ty + i * 8;
    t[ty + i * 8][tx] = x[c * HW + bp * 32 + tx];
  }
  __syncthreads();
#pragma unroll
  for (int i = 0; i < 4; i++) {
    int p = bp * 32 + ty + i * 8;
    xt[p * NC + bc * 32 + tx] = (f16)t[tx][ty + i * 8];
  }
}

// ------------------- GEMM1: qkv = Wpw[768,256] * x  (+bias) ----------------
// A = W row-major [768][256] fp16, B^T = xt [4096][256] fp16.
// Wave tile 16(m) x 64(n); block = 4 waves -> 64m x 64n.
__global__ __launch_bounds__(256) void k_gemm_qkv(
    const f16* __restrict__ w, const f16* __restrict__ xt,
    const float* __restrict__ bias, float* __restrict__ out) {
  int bm = blockIdx.x >> 6;   // 12
  int bn = blockIdx.x & 63;   // 64
  int wave = threadIdx.x >> 6, lane = threadIdx.x & 63;
  int r = lane & 15, g = lane >> 4;
  int m_row = bm * 64 + wave * 16 + r;
  int n0 = bn * 64;
  f32x4 acc[4] = {};
  for (int kk = 0; kk < NC; kk += 32) {
    f16x8 a = *(const f16x8*)&w[m_row * NC + kk + g * 8];
#pragma unroll
    for (int nt = 0; nt < 4; nt++) {
      f16x8 b = *(const f16x8*)&xt[(n0 + nt * 16 + r) * NC + kk + g * 8];
      acc[nt] = mfma16(a, b, acc[nt]);
    }
  }
  int mbase = bm * 64 + wave * 16 + g * 4;
  float bj[4];
#pragma unroll
  for (int j = 0; j < 4; j++) bj[j] = bias[mbase + j];
#pragma unroll
  for (int nt = 0; nt < 4; nt++)
#pragma unroll
    for (int j = 0; j < 4; j++)
      out[(mbase + j) * HW + n0 + nt * 16 + r] = acc[nt][j] + bj[j];
}

// ------------------- depthwise 11x11, pad 5, groups=768 --------------------
// One block per channel. Image staged padded in LDS (74x74). Each thread
// computes 2 groups of 8 consecutive-x pixels with register row reuse.
// Scatter to attention layouts: q,k n-major [h][n][d], v c-major [h][d][n].
// q is pre-scaled by 1/temp = 0.2.
__global__ __launch_bounds__(256) void k_dwconv(
    const float* __restrict__ qkv, const float* __restrict__ wdw,
    const float* __restrict__ bdw, f16* __restrict__ q_nm,
    f16* __restrict__ k_nm, f16* __restrict__ v_cm) {
  __shared__ float img[74 * 74];
  __shared__ float wgt[121];
  int c = blockIdx.x;
  int tid = threadIdx.x;
  for (int i = tid; i < 74 * 74; i += 256) {
    int row = i / 74, col = i - row * 74;
    int y = row - 5, xx = col - 5;
    img[i] = ((unsigned)y < 64u && (unsigned)xx < 64u) ? qkv[c * HW + y * 64 + xx]
                                                       : 0.f;
  }
  for (int i = tid; i < 121; i += 256) wgt[i] = wdw[c * 121 + i];
  __syncthreads();
  float bias = bdw[c];
#pragma unroll
  for (int it = 0; it < 2; it++) {
    int gi = it * 256 + tid;
    int px0 = gi * 8;
    int y = px0 >> 6, x0 = px0 & 63;
    float acc[8] = {};
#pragma unroll
    for (int ky = 0; ky < 11; ky++) {
      const float* rp = &img[(y + ky) * 74 + x0];
      float rv[18];
#pragma unroll
      for (int t = 0; t < 18; t++) rv[t] = rp[t];
#pragma unroll
      for (int kx = 0; kx < 11; kx++) {
        float wv = wgt[ky * 11 + kx];
#pragma unroll
        for (int p = 0; p < 8; p++) acc[p] = fmaf(rv[kx + p], wv, acc[p]);
      }
    }
    if (c < 256) {
      int h = c >> 5, d = c & 31;
#pragma unroll
      for (int p = 0; p < 8; p++)
        q_nm[(h * HW + px0 + p) * 32 + d] = (f16)((acc[p] + bias) * 0.2f);
    } else if (c < 512) {
      int cc = c - 256;
      int h = cc >> 5, d = cc & 31;
#pragma unroll
      for (int p = 0; p < 8; p++)
        k_nm[(h * HW + px0 + p) * 32 + d] = (f16)(acc[p] + bias);
    } else {
      int cc = c - 512;
#pragma unroll
      for (int p = 0; p < 8; p++)
        v_cm[cc * HW + px0 + p] = (f16)(acc[p] + bias);
    }
  }
}

// ----------------------------- flash attention -----------------------------
// Per wave: 16 q rows, online softmax over all 4096 keys in chunks of 32.
// Scores computed transposed: S^T = mfma(A=K_tile(16m x 32d, row-permuted),
// B=Q(32d x 16n)). Row permutation perm(r)=8*(r>>2)+(r&3) makes the score
// C/D layout coincide with the PV MFMA A-fragment layout -> P never leaves
// registers. PV: O[n][d] += mfma(A=P(16n x 32m), B=V^T(32m x 16d)).
__global__ __launch_bounds__(256) void k_attn(
    const f16* __restrict__ q_nm, const f16* __restrict__ k_nm,
    const f16* __restrict__ v_cm, f16* __restrict__ newx) {
  int h = blockIdx.x >> 6;   // 8 heads
  int qb = blockIdx.x & 63;  // 64 q-blocks of 64 rows
  int wave = threadIdx.x >> 6, lane = threadIdx.x & 63;
  int r = lane & 15, g = lane >> 4;
  int n_base = qb * 64 + wave * 16;
  const f16* qh = q_nm + h * HW * 32;
  const f16* kh = k_nm + h * HW * 32;
  const f16* vh = v_cm + h * 32 * HW;

  f16x8 bq = *(const f16x8*)&qh[(n_base + r) * 32 + g * 8];
  int pr = ((r & 12) << 1) | (r & 3);  // 8*(r>>2)+(r&3)
  const float L2E = 1.44269504088896f;
  const f32x4 zero = {0.f, 0.f, 0.f, 0.f};

  f32x4 acc0 = zero, acc1 = zero;
  float M = -1e30f, L = 0.f;

  for (int m0 = 0; m0 < HW; m0 += 32) {
    f16x8 ak0 = *(const f16x8*)&kh[(m0 + pr) * 32 + g * 8];
    f16x8 ak1 = *(const f16x8*)&kh[(m0 + pr + 4) * 32 + g * 8];
    f32x4 s0 = mfma16(ak0, bq, zero);  // m = m0+8g+j, n = n_base+r
    f32x4 s1 = mfma16(ak1, bq, zero);  // m = m0+8g+4+j
    f16x8 bv0 = *(const f16x8*)&vh[r * HW + m0 + g * 8];
    f16x8 bv1 = *(const f16x8*)&vh[(16 + r) * HW + m0 + g * 8];

    float lm = fmaxf(fmaxf(fmaxf(s0[0], s0[1]), fmaxf(s0[2], s0[3])),
                     fmaxf(fmaxf(s1[0], s1[1]), fmaxf(s1[2], s1[3])));
    lm = fmaxf(lm, __shfl_xor(lm, 16));
    lm = fmaxf(lm, __shfl_xor(lm, 32));
    float Mn = fmaxf(M, lm);
    float rs = exp2f((M - Mn) * L2E);
    float p[8];
#pragma unroll
    for (int j = 0; j < 4; j++) p[j] = exp2f((s0[j] - Mn) * L2E);
#pragma unroll
    for (int j = 0; j < 4; j++) p[4 + j] = exp2f((s1[j] - Mn) * L2E);
    float ps = ((p[0] + p[1]) + (p[2] + p[3])) + ((p[4] + p[5]) + (p[6] + p[7]));
    ps += __shfl_xor(ps, 16);
    ps += __shfl_xor(ps, 32);
    L = L * rs + ps;
    M = Mn;
    f16x8 pa;
#pragma unroll
    for (int j = 0; j < 8; j++) pa[j] = (f16)p[j];
#pragma unroll
    for (int j = 0; j < 4; j++) {
      float rj = __shfl(rs, g * 4 + j);  // rescale for out-row n_base+4g+j
      acc0[j] *= rj;
      acc1[j] *= rj;
    }
    acc0 = mfma16(pa, bv0, acc0);
    acc1 = mfma16(pa, bv1, acc1);
  }
  float il = 1.f / L;
#pragma unroll
  for (int j = 0; j < 4; j++) {
    float ilj = __shfl(il, g * 4 + j);
    int n = n_base + g * 4 + j;
    newx[n * NC + h * 32 + r] = (f16)(acc0[j] * ilj);
    newx[n * NC + h * 32 + 16 + r] = (f16)(acc1[j] * ilj);
  }
}

// ---------- GEMM2: out = relu(Wlin[256,256] * newx + b) + x ----------------
__global__ __launch_bounds__(256) void k_gemm_proj(
    const f16* __restrict__ w, const f16* __restrict__ nx,
    const float* __restrict__ bias, const float* __restrict__ x,
    float* __restrict__ out) {
  int bm = blockIdx.x >> 6;  // 4
  int bn = blockIdx.x & 63;  // 64
  int wave = threadIdx.x >> 6, lane = threadIdx.x & 63;
  int r = lane & 15, g = lane >> 4;
  int m_row = bm * 64 + wave * 16 + r;
  int n0 = bn * 64;
  f32x4 acc[4] = {};
  for (int kk = 0; kk < NC; kk += 32) {
    f16x8 a = *(const f16x8*)&w[m_row * NC + kk + g * 8];
#pragma unroll
    for (int nt = 0; nt < 4; nt++) {
      f16x8 b = *(const f16x8*)&nx[(n0 + nt * 16 + r) * NC + kk + g * 8];
      acc[nt] = mfma16(a, b, acc[nt]);
    }
  }
  int mbase = bm * 64 + wave * 16 + g * 4;
  float bj[4];
#pragma unroll
  for (int j = 0; j < 4; j++) bj[j] = bias[mbase + j];
#pragma unroll
  for (int nt = 0; nt < 4; nt++)
#pragma unroll
    for (int j = 0; j < 4; j++) {
      int m = mbase + j, n = n0 + nt * 16 + r;
      float v = fmaxf(acc[nt][j] + bj[j], 0.f) + x[m * HW + n];
      out[m * HW + n] = v;
    }
}

// ---------------------------------------------------------------------------
extern "C" void kernel_launch(void* const* d_in, const int* in_sizes, int n_in,
                              void* d_out, int out_size, void* d_ws,
                              size_t ws_size, hipStream_t stream) {
  const float* x = (const float*)d_in[0];
  const float* w_pw = (const float*)d_in[1];
  const float* b_pw = (const float*)d_in[2];
  const float* w_dw = (const float*)d_in[3];
  const float* b_dw = (const float*)d_in[4];
  const float* w_lin = (const float*)d_in[5];
  const float* b_lin = (const float*)d_in[6];
  float* out = (float*)d_out;

  char* ws = (char*)d_ws;
  f16* wpw_h = (f16*)(ws + 0);          // 768*256*2      = 393216
  f16* wlin_h = (f16*)(ws + 393216);    // 256*256*2      = 131072
  f16* xt = (f16*)(ws + 524288);        // 4096*256*2     = 2097152
  float* qkv = (float*)(ws + 2621440);  // 768*4096*4     = 12582912
  f16* q_nm = (f16*)(ws + 15204352);    // 8*4096*32*2    = 2097152
  f16* k_nm = (f16*)(ws + 17301504);    // 2097152
  f16* v_cm = (f16*)(ws + 19398656);    // 2097152
  f16* nx = (f16*)(ws + 21495808);      // 2097152 -> total 23592960 bytes

  k_prep_w<<<512, 256, 0, stream>>>(w_pw, w_lin, wpw_h, wlin_h);
  k_transpose_x<<<1024, 256, 0, stream>>>(x, xt);
  k_gemm_qkv<<<768, 256, 0, stream>>>(wpw_h, xt, b_pw, qkv);
  k_dwconv<<<768, 256, 0, stream>>>(qkv, w_dw, b_dw, q_nm, k_nm, v_cm);
  k_attn<<<512, 256, 0, stream>>>(q_nm, k_nm, v_cm, nx);
  k_gemm_proj<<<256, 256, 0, stream>>>(wlin_h, nx, b_lin, x, out);
}

// Round 2
// 155.292 us; speedup vs baseline: 1.0104x; 1.0104x over previous
//
#include <hip/hip_runtime.h>

// ---------------------------------------------------------------------------
// attention_76089640615954 on MI355X (gfx950)
// x:[1,256,64,64] -> 1x1 conv (3C) -> 11x11 depthwise -> 8-head attn (N=4096,
// d=32, temp=5) -> 1x1 conv + bias -> relu + residual.
// fp16 MFMA (16x16x32) for GEMM-shaped work, fp32 accumulate.
// R1: k_attn rebuilt as split-K flash decoding (4 waves x 1024 keys per
//     16-row q tile, LDS LSE-combine), defer-max threshold, base-2 softmax
//     folded into q pre-scale. Attacks the 101us latency-bound k_attn.
// ---------------------------------------------------------------------------

typedef _Float16 f16;
typedef _Float16 f16x8 __attribute__((ext_vector_type(8)));
typedef float f32x4 __attribute__((ext_vector_type(4)));

#define HW 4096      // 64*64 pixels
#define NC 256       // channels

static __device__ __forceinline__ f32x4 mfma16(f16x8 a, f16x8 b, f32x4 c) {
  return __builtin_amdgcn_mfma_f32_16x16x32_f16(a, b, c, 0, 0, 0);
}

// --------------------------- prep: weights -> fp16 -------------------------
__global__ __launch_bounds__(256) void k_prep_w(
    const float* __restrict__ wpw, const float* __restrict__ wlin,
    f16* __restrict__ wpw_h, f16* __restrict__ wlin_h) {
  int i = blockIdx.x * 256 + threadIdx.x;
  int stride = gridDim.x * 256;
  for (int idx = i; idx < 3 * NC * NC; idx += stride) wpw_h[idx] = (f16)wpw[idx];
  for (int idx = i; idx < NC * NC; idx += stride) wlin_h[idx] = (f16)wlin[idx];
}

// --------------------------- prep: x -> xt[p][c] fp16 ----------------------
__global__ __launch_bounds__(256) void k_transpose_x(
    const float* __restrict__ x, f16* __restrict__ xt) {
  __shared__ float t[32][33];
  int bc = blockIdx.x >> 7;    // 8 channel tiles of 32
  int bp = blockIdx.x & 127;   // 128 pixel tiles of 32
  int tx = threadIdx.x & 31, ty = threadIdx.x >> 5;  // ty 0..7
#pragma unroll
  for (int i = 0; i < 4; i++) {
    int c = bc * 32 + ty + i * 8;
    t[ty + i * 8][tx] = x[c * HW + bp * 32 + tx];
  }
  __syncthreads();
#pragma unroll
  for (int i = 0; i < 4; i++) {
    int p = bp * 32 + ty + i * 8;
    xt[p * NC + bc * 32 + tx] = (f16)t[tx][ty + i * 8];
  }
}

// ------------------- GEMM1: qkv = Wpw[768,256] * x  (+bias) ----------------
__global__ __launch_bounds__(256) void k_gemm_qkv(
    const f16* __restrict__ w, const f16* __restrict__ xt,
    const float* __restrict__ bias, float* __restrict__ out) {
  int bm = blockIdx.x >> 6;   // 12
  int bn = blockIdx.x & 63;   // 64
  int wave = threadIdx.x >> 6, lane = threadIdx.x & 63;
  int r = lane & 15, g = lane >> 4;
  int m_row = bm * 64 + wave * 16 + r;
  int n0 = bn * 64;
  f32x4 acc[4] = {};
  for (int kk = 0; kk < NC; kk += 32) {
    f16x8 a = *(const f16x8*)&w[m_row * NC + kk + g * 8];
#pragma unroll
    for (int nt = 0; nt < 4; nt++) {
      f16x8 b = *(const f16x8*)&xt[(n0 + nt * 16 + r) * NC + kk + g * 8];
      acc[nt] = mfma16(a, b, acc[nt]);
    }
  }
  int mbase = bm * 64 + wave * 16 + g * 4;
  float bj[4];
#pragma unroll
  for (int j = 0; j < 4; j++) bj[j] = bias[mbase + j];
#pragma unroll
  for (int nt = 0; nt < 4; nt++)
#pragma unroll
    for (int j = 0; j < 4; j++)
      out[(mbase + j) * HW + n0 + nt * 16 + r] = acc[nt][j] + bj[j];
}

// ------------------- depthwise 11x11, pad 5, groups=768 --------------------
// q is pre-scaled by (1/temp)*log2(e) so softmax runs natively base-2.
__global__ __launch_bounds__(256) void k_dwconv(
    const float* __restrict__ qkv, const float* __restrict__ wdw,
    const float* __restrict__ bdw, f16* __restrict__ q_nm,
    f16* __restrict__ k_nm, f16* __restrict__ v_cm) {
  __shared__ float img[74 * 74];
  __shared__ float wgt[121];
  int c = blockIdx.x;
  int tid = threadIdx.x;
  for (int i = tid; i < 74 * 74; i += 256) {
    int row = i / 74, col = i - row * 74;
    int y = row - 5, xx = col - 5;
    img[i] = ((unsigned)y < 64u && (unsigned)xx < 64u) ? qkv[c * HW + y * 64 + xx]
                                                       : 0.f;
  }
  for (int i = tid; i < 121; i += 256) wgt[i] = wdw[c * 121 + i];
  __syncthreads();
  float bias = bdw[c];
#pragma unroll
  for (int it = 0; it < 2; it++) {
    int gi = it * 256 + tid;
    int px0 = gi * 8;
    int y = px0 >> 6, x0 = px0 & 63;
    float acc[8] = {};
#pragma unroll
    for (int ky = 0; ky < 11; ky++) {
      const float* rp = &img[(y + ky) * 74 + x0];
      float rv[18];
#pragma unroll
      for (int t = 0; t < 18; t++) rv[t] = rp[t];
#pragma unroll
      for (int kx = 0; kx < 11; kx++) {
        float wv = wgt[ky * 11 + kx];
#pragma unroll
        for (int p = 0; p < 8; p++) acc[p] = fmaf(rv[kx + p], wv, acc[p]);
      }
    }
    if (c < 256) {
      int h = c >> 5, d = c & 31;
#pragma unroll
      for (int p = 0; p < 8; p++)
        q_nm[(h * HW + px0 + p) * 32 + d] =
            (f16)((acc[p] + bias) * 0.28853900817779268f);  // 0.2*log2(e)
    } else if (c < 512) {
      int cc = c - 256;
      int h = cc >> 5, d = cc & 31;
#pragma unroll
      for (int p = 0; p < 8; p++)
        k_nm[(h * HW + px0 + p) * 32 + d] = (f16)(acc[p] + bias);
    } else {
      int cc = c - 512;
#pragma unroll
      for (int p = 0; p < 8; p++)
        v_cm[cc * HW + px0 + p] = (f16)(acc[p] + bias);
    }
  }
}

// ----------------------------- flash attention -----------------------------
// Split-K flash decoding: block = 16 q rows; wave w handles keys
// [w*1024,(w+1)*1024) with private online softmax (base-2 domain, defer-max),
// partials (O, M, L) merged via LDS log-sum-exp combine.
// Scores transposed: S^T = mfma(A=K_tile row-permuted, B=Q). perm(r)=
// 8*(r>>2)+(r&3) makes score C/D layout == PV A-fragment layout (P stays in
// registers). PV: O += mfma(A=P, B=V^T).
__global__ __launch_bounds__(256, 8) void k_attn(
    const f16* __restrict__ q_nm, const f16* __restrict__ k_nm,
    const f16* __restrict__ v_cm, f16* __restrict__ newx) {
  __shared__ float s_acc[4][16][33];
  __shared__ float s_M[4][16];
  __shared__ float s_L[4][16];
  int h = blockIdx.x >> 8;   // 8 heads
  int qt = blockIdx.x & 255; // 256 q tiles of 16 rows
  int wave = threadIdx.x >> 6, lane = threadIdx.x & 63;
  int r = lane & 15, g = lane >> 4;
  int n_base = qt * 16;
  const f16* qh = q_nm + h * (HW * 32);
  const f16* kh = k_nm + h * (HW * 32);
  const f16* vh = v_cm + h * (32 * HW);

  f16x8 bq = *(const f16x8*)&qh[(n_base + r) * 32 + g * 8];
  int pr = ((r & 12) << 1) | (r & 3);  // 8*(r>>2)+(r&3)
  const f32x4 zero = {0.f, 0.f, 0.f, 0.f};
  f32x4 acc0 = zero, acc1 = zero;
  float M = -1e30f, L = 0.f;

  int m_lo = wave << 10;
  const f16* kp = kh + (m_lo + pr) * 32 + g * 8;
  const f16* vp0 = vh + r * HW + m_lo + g * 8;
  const f16* vp1 = vp0 + 16 * HW;

  for (int it = 0; it < 32; ++it) {
    f16x8 ak0 = *(const f16x8*)(kp);
    f16x8 ak1 = *(const f16x8*)(kp + 128);
    f16x8 bv0 = *(const f16x8*)(vp0);
    f16x8 bv1 = *(const f16x8*)(vp1);
    kp += 1024;  // 32 keys * 32 d
    vp0 += 32;
    vp1 += 32;
    f32x4 s0 = mfma16(ak0, bq, zero);  // key m0+8g+j,   q row n_base+r
    f32x4 s1 = mfma16(ak1, bq, zero);  // key m0+8g+4+j, q row n_base+r
    float lm = fmaxf(fmaxf(fmaxf(s0[0], s0[1]), fmaxf(s0[2], s0[3])),
                     fmaxf(fmaxf(s1[0], s1[1]), fmaxf(s1[2], s1[3])));
    lm = fmaxf(lm, __shfl_xor(lm, 16));
    lm = fmaxf(lm, __shfl_xor(lm, 32));
    float p[8];
    if (__all(lm <= M + 8.f)) {
      // fast path: max didn't grow enough to matter; p <= 2^8, f16-safe
#pragma unroll
      for (int j = 0; j < 4; j++) p[j] = exp2f(s0[j] - M);
#pragma unroll
      for (int j = 0; j < 4; j++) p[4 + j] = exp2f(s1[j] - M);
    } else {
      float Mn = fmaxf(M, lm);
      float rs = exp2f(M - Mn);
#pragma unroll
      for (int j = 0; j < 4; j++) p[j] = exp2f(s0[j] - Mn);
#pragma unroll
      for (int j = 0; j < 4; j++) p[4 + j] = exp2f(s1[j] - Mn);
      L *= rs;
#pragma unroll
      for (int j = 0; j < 4; j++) {
        float rj = __shfl(rs, 4 * g + j);  // rescale for out-row n_base+4g+j
        acc0[j] *= rj;
        acc1[j] *= rj;
      }
      M = Mn;
    }
    float ps =
        ((p[0] + p[1]) + (p[2] + p[3])) + ((p[4] + p[5]) + (p[6] + p[7]));
    ps += __shfl_xor(ps, 16);
    ps += __shfl_xor(ps, 32);
    L += ps;
    f16x8 pa;
#pragma unroll
    for (int j = 0; j < 8; j++) pa[j] = (f16)p[j];
    acc0 = mfma16(pa, bv0, acc0);
    acc1 = mfma16(pa, bv1, acc1);
  }
  // ---- write per-wave partials (acc relative to per-wave M) ----
#pragma unroll
  for (int j = 0; j < 4; j++) {
    s_acc[wave][4 * g + j][r] = acc0[j];
    s_acc[wave][4 * g + j][16 + r] = acc1[j];
  }
  if (g == 0) {
    s_M[wave][r] = M;
    s_L[wave][r] = L;
  }
  __syncthreads();
  // ---- LSE combine across the 4 key-quarters ----
  for (int idx = threadIdx.x; idx < 512; idx += 256) {
    int row = idx >> 5, d = idx & 31;
    float m0 = s_M[0][row], m1 = s_M[1][row], m2 = s_M[2][row],
          m3 = s_M[3][row];
    float mm = fmaxf(fmaxf(m0, m1), fmaxf(m2, m3));
    float e0 = exp2f(m0 - mm), e1 = exp2f(m1 - mm), e2 = exp2f(m2 - mm),
          e3 = exp2f(m3 - mm);
    float Lc = e0 * s_L[0][row] + e1 * s_L[1][row] + e2 * s_L[2][row] +
               e3 * s_L[3][row];
    float Oc = e0 * s_acc[0][row][d] + e1 * s_acc[1][row][d] +
               e2 * s_acc[2][row][d] + e3 * s_acc[3][row][d];
    newx[(n_base + row) * NC + h * 32 + d] = (f16)(Oc / Lc);
  }
}

// ---------- GEMM2: out = relu(Wlin[256,256] * newx + b) + x ----------------
__global__ __launch_bounds__(256) void k_gemm_proj(
    const f16* __restrict__ w, const f16* __restrict__ nx,
    const float* __restrict__ bias, const float* __restrict__ x,
    float* __restrict__ out) {
  int bm = blockIdx.x >> 6;  // 4
  int bn = blockIdx.x & 63;  // 64
  int wave = threadIdx.x >> 6, lane = threadIdx.x & 63;
  int r = lane & 15, g = lane >> 4;
  int m_row = bm * 64 + wave * 16 + r;
  int n0 = bn * 64;
  f32x4 acc[4] = {};
  for (int kk = 0; kk < NC; kk += 32) {
    f16x8 a = *(const f16x8*)&w[m_row * NC + kk + g * 8];
#pragma unroll
    for (int nt = 0; nt < 4; nt++) {
      f16x8 b = *(const f16x8*)&nx[(n0 + nt * 16 + r) * NC + kk + g * 8];
      acc[nt] = mfma16(a, b, acc[nt]);
    }
  }
  int mbase = bm * 64 + wave * 16 + g * 4;
  float bj[4];
#pragma unroll
  for (int j = 0; j < 4; j++) bj[j] = bias[mbase + j];
#pragma unroll
  for (int nt = 0; nt < 4; nt++)
#pragma unroll
    for (int j = 0; j < 4; j++) {
      int m = mbase + j, n = n0 + nt * 16 + r;
      float v = fmaxf(acc[nt][j] + bj[j], 0.f) + x[m * HW + n];
      out[m * HW + n] = v;
    }
}

// ---------------------------------------------------------------------------
extern "C" void kernel_launch(void* const* d_in, const int* in_sizes, int n_in,
                              void* d_out, int out_size, void* d_ws,
                              size_t ws_size, hipStream_t stream) {
  const float* x = (const float*)d_in[0];
  const float* w_pw = (const float*)d_in[1];
  const float* b_pw = (const float*)d_in[2];
  const float* w_dw = (const float*)d_in[3];
  const float* b_dw = (const float*)d_in[4];
  const float* w_lin = (const float*)d_in[5];
  const float* b_lin = (const float*)d_in[6];
  float* out = (float*)d_out;

  char* ws = (char*)d_ws;
  f16* wpw_h = (f16*)(ws + 0);          // 768*256*2      = 393216
  f16* wlin_h = (f16*)(ws + 393216);    // 256*256*2      = 131072
  f16* xt = (f16*)(ws + 524288);        // 4096*256*2     = 2097152
  float* qkv = (float*)(ws + 2621440);  // 768*4096*4     = 12582912
  f16* q_nm = (f16*)(ws + 15204352);    // 8*4096*32*2    = 2097152
  f16* k_nm = (f16*)(ws + 17301504);    // 2097152
  f16* v_cm = (f16*)(ws + 19398656);    // 2097152
  f16* nx = (f16*)(ws + 21495808);      // 2097152 -> total 23592960 bytes

  k_prep_w<<<512, 256, 0, stream>>>(w_pw, w_lin, wpw_h, wlin_h);
  k_transpose_x<<<1024, 256, 0, stream>>>(x, xt);
  k_gemm_qkv<<<768, 256, 0, stream>>>(wpw_h, xt, b_pw, qkv);
  k_dwconv<<<768, 256, 0, stream>>>(qkv, w_dw, b_dw, q_nm, k_nm, v_cm);
  k_attn<<<2048, 256, 0, stream>>>(q_nm, k_nm, v_cm, nx);
  k_gemm_proj<<<256, 256, 0, stream>>>(wlin_h, nx, b_lin, x, out);
}

// Round 3
// 116.669 us; speedup vs baseline: 1.3449x; 1.3310x over previous
//
#include <hip/hip_runtime.h>

// ---------------------------------------------------------------------------
// attention_76089640615954 on MI355X (gfx950)
// x:[1,256,64,64] -> 1x1 conv (3C) -> 11x11 depthwise -> 8-head attn (N=4096,
// d=32, temp=5) -> 1x1 conv + bias -> relu + residual.
// fp16 MFMA (16x16x32) for GEMM-shaped work, fp32 accumulate.
// R2 evidence: occupancy 21.6->62% left k_attn at 101us (MfmaUtil 6.9,
// VALUBusy 52) -> throughput-bound on per-iteration softmax VALU, not latency.
// R3: fixed-shift softmax. Per-row Cauchy-Schwarz bound M_r = ||q_r||*max||k||
// (precomputed by k_norms) replaces the online max: P = exp2(s - (M_r-13.9))
// <= 2^13.9 fits f16; the 2^shift factor cancels in O/L. Main loop now has
// ZERO cross-lane ops, ZERO branches; exp2 via raw v_exp_f32 builtin; 32
// q-rows per wave halves K/V traffic.
// ---------------------------------------------------------------------------

typedef _Float16 f16;
typedef _Float16 f16x8 __attribute__((ext_vector_type(8)));
typedef float f32x4 __attribute__((ext_vector_type(4)));

#define HW 4096      // 64*64 pixels
#define NC 256       // channels

#if __has_builtin(__builtin_amdgcn_exp2f)
#define EXP2(x) __builtin_amdgcn_exp2f(x)
#else
#define EXP2(x) exp2f(x)
#endif

static __device__ __forceinline__ f32x4 mfma16(f16x8 a, f16x8 b, f32x4 c) {
  return __builtin_amdgcn_mfma_f32_16x16x32_f16(a, b, c, 0, 0, 0);
}

// --------------------------- prep: weights -> fp16 -------------------------
__global__ __launch_bounds__(256) void k_prep_w(
    const float* __restrict__ wpw, const float* __restrict__ wlin,
    f16* __restrict__ wpw_h, f16* __restrict__ wlin_h,
    int* __restrict__ kmax_bits) {
  int i = blockIdx.x * 256 + threadIdx.x;
  if (i < 8) kmax_bits[i] = 0;  // init for k_norms' atomicMax
  int stride = gridDim.x * 256;
  for (int idx = i; idx < 3 * NC * NC; idx += stride) wpw_h[idx] = (f16)wpw[idx];
  for (int idx = i; idx < NC * NC; idx += stride) wlin_h[idx] = (f16)wlin[idx];
}

// --------------------------- prep: x -> xt[p][c] fp16 ----------------------
__global__ __launch_bounds__(256) void k_transpose_x(
    const float* __restrict__ x, f16* __restrict__ xt) {
  __shared__ float t[32][33];
  int bc = blockIdx.x >> 7;    // 8 channel tiles of 32
  int bp = blockIdx.x & 127;   // 128 pixel tiles of 32
  int tx = threadIdx.x & 31, ty = threadIdx.x >> 5;  // ty 0..7
#pragma unroll
  for (int i = 0; i < 4; i++) {
    int c = bc * 32 + ty + i * 8;
    t[ty + i * 8][tx] = x[c * HW + bp * 32 + tx];
  }
  __syncthreads();
#pragma unroll
  for (int i = 0; i < 4; i++) {
    int p = bp * 32 + ty + i * 8;
    xt[p * NC + bc * 32 + tx] = (f16)t[tx][ty + i * 8];
  }
}

// ------------------- GEMM1: qkv = Wpw[768,256] * x  (+bias) ----------------
__global__ __launch_bounds__(256) void k_gemm_qkv(
    const f16* __restrict__ w, const f16* __restrict__ xt,
    const float* __restrict__ bias, float* __restrict__ out) {
  int bm = blockIdx.x >> 6;   // 12
  int bn = blockIdx.x & 63;   // 64
  int wave = threadIdx.x >> 6, lane = threadIdx.x & 63;
  int r = lane & 15, g = lane >> 4;
  int m_row = bm * 64 + wave * 16 + r;
  int n0 = bn * 64;
  f32x4 acc[4] = {};
  for (int kk = 0; kk < NC; kk += 32) {
    f16x8 a = *(const f16x8*)&w[m_row * NC + kk + g * 8];
#pragma unroll
    for (int nt = 0; nt < 4; nt++) {
      f16x8 b = *(const f16x8*)&xt[(n0 + nt * 16 + r) * NC + kk + g * 8];
      acc[nt] = mfma16(a, b, acc[nt]);
    }
  }
  int mbase = bm * 64 + wave * 16 + g * 4;
  float bj[4];
#pragma unroll
  for (int j = 0; j < 4; j++) bj[j] = bias[mbase + j];
#pragma unroll
  for (int nt = 0; nt < 4; nt++)
#pragma unroll
    for (int j = 0; j < 4; j++)
      out[(mbase + j) * HW + n0 + nt * 16 + r] = acc[nt][j] + bj[j];
}

// ------------------- depthwise 11x11, pad 5, groups=768 --------------------
// q is pre-scaled by (1/temp)*log2(e) so softmax runs natively base-2.
__global__ __launch_bounds__(256) void k_dwconv(
    const float* __restrict__ qkv, const float* __restrict__ wdw,
    const float* __restrict__ bdw, f16* __restrict__ q_nm,
    f16* __restrict__ k_nm, f16* __restrict__ v_cm) {
  __shared__ float img[74 * 74];
  __shared__ float wgt[121];
  int c = blockIdx.x;
  int tid = threadIdx.x;
  for (int i = tid; i < 74 * 74; i += 256) {
    int row = i / 74, col = i - row * 74;
    int y = row - 5, xx = col - 5;
    img[i] = ((unsigned)y < 64u && (unsigned)xx < 64u) ? qkv[c * HW + y * 64 + xx]
                                                       : 0.f;
  }
  for (int i = tid; i < 121; i += 256) wgt[i] = wdw[c * 121 + i];
  __syncthreads();
  float bias = bdw[c];
#pragma unroll
  for (int it = 0; it < 2; it++) {
    int gi = it * 256 + tid;
    int px0 = gi * 8;
    int y = px0 >> 6, x0 = px0 & 63;
    float acc[8] = {};
#pragma unroll
    for (int ky = 0; ky < 11; ky++) {
      const float* rp = &img[(y + ky) * 74 + x0];
      float rv[18];
#pragma unroll
      for (int t = 0; t < 18; t++) rv[t] = rp[t];
#pragma unroll
      for (int kx = 0; kx < 11; kx++) {
        float wv = wgt[ky * 11 + kx];
#pragma unroll
        for (int p = 0; p < 8; p++) acc[p] = fmaf(rv[kx + p], wv, acc[p]);
      }
    }
    if (c < 256) {
      int h = c >> 5, d = c & 31;
#pragma unroll
      for (int p = 0; p < 8; p++)
        q_nm[(h * HW + px0 + p) * 32 + d] =
            (f16)((acc[p] + bias) * 0.28853900817779268f);  // 0.2*log2(e)
    } else if (c < 512) {
      int cc = c - 256;
      int h = cc >> 5, d = cc & 31;
#pragma unroll
      for (int p = 0; p < 8; p++)
        k_nm[(h * HW + px0 + p) * 32 + d] = (f16)(acc[p] + bias);
    } else {
      int cc = c - 512;
#pragma unroll
      for (int p = 0; p < 8; p++)
        v_cm[cc * HW + px0 + p] = (f16)(acc[p] + bias);
    }
  }
}

// ---------------- norms: ||q_row|| per row, max ||k_row|| per head ---------
// q_bound[row] = ||q_row|| (q already carries the 0.2886 prescale, so this is
// directly the base-2 score bound per unit ||k||).
__global__ __launch_bounds__(256) void k_norms(
    const f16* __restrict__ q_nm, const f16* __restrict__ k_nm,
    float* __restrict__ q_bound, int* __restrict__ kmax_bits) {
  __shared__ float red[256];
  int b = blockIdx.x, t = threadIdx.x;
  const f16* src = (b < 128) ? q_nm : k_nm;
  int row = ((b & 127) * 256) + t;
  const f16x8* p = (const f16x8*)&src[row * 32];
  float s = 0.f;
#pragma unroll
  for (int i = 0; i < 4; i++) {
    f16x8 v = p[i];
#pragma unroll
    for (int j = 0; j < 8; j++) {
      float f = (float)v[j];
      s = fmaf(f, f, s);
    }
  }
  float nrm = sqrtf(s);
  if (b < 128) {
    q_bound[row] = nrm;
  } else {
    red[t] = nrm;
    __syncthreads();
    for (int off = 128; off > 0; off >>= 1) {
      if (t < off) red[t] = fmaxf(red[t], red[t + off]);
      __syncthreads();
    }
    // all 4096 rows of a head span 16 consecutive blocks -> row>>12 is head
    if (t == 0) atomicMax(&kmax_bits[row >> 12], __float_as_int(red[0]));
  }
}

// ----------------------------- flash attention -----------------------------
// Block = 32 q rows; wave w handles keys [w*1024,(w+1)*1024). Fixed-shift
// softmax: P = exp2(s - C_row), C_row = ||q_row||*maxk - 13.9 (s <= bound by
// Cauchy-Schwarz => P <= 2^13.9, f16-safe; shift cancels in O/L). Main loop:
// no cross-lane ops, no branches. Partial O (32x32) and L summed across the
// 4 waves in LDS (same scale -> plain add).
// Scores transposed: S^T = mfma(A=K_tile row-permuted pr(i)=8*(i>>2)+(i&3),
// B=Q) so score C/D layout == PV A-fragment layout; P stays in registers.
__global__ __launch_bounds__(256, 4) void k_attn(
    const f16* __restrict__ q_nm, const f16* __restrict__ k_nm,
    const f16* __restrict__ v_cm, const float* __restrict__ q_bound,
    const int* __restrict__ kmax_bits, f16* __restrict__ newx) {
  __shared__ float s_acc[4][32][33];
  __shared__ float s_L[4][32];
  int h = blockIdx.x >> 7;    // 8 heads
  int qt = blockIdx.x & 127;  // 128 q tiles of 32 rows
  int wave = threadIdx.x >> 6, lane = threadIdx.x & 63;
  int r = lane & 15, g = lane >> 4;
  int n_base = qt * 32;
  const f16* qh = q_nm + h * (HW * 32);
  const f16* kh = k_nm + h * (HW * 32);
  const f16* vh = v_cm + h * (32 * HW);

  f16x8 bq0 = *(const f16x8*)&qh[(n_base + r) * 32 + g * 8];
  f16x8 bq1 = *(const f16x8*)&qh[(n_base + 16 + r) * 32 + g * 8];
  float kmax = __int_as_float(kmax_bits[h]);
  float Ca = fmaf(q_bound[h * HW + n_base + r], kmax, -13.9f);
  float Cb = fmaf(q_bound[h * HW + n_base + 16 + r], kmax, -13.9f);

  int pr = ((r & 12) << 1) | (r & 3);  // 8*(r>>2)+(r&3)
  const f32x4 zero = {0.f, 0.f, 0.f, 0.f};
  f32x4 accA0 = zero, accA1 = zero, accB0 = zero, accB1 = zero;
  float La = 0.f, Lb = 0.f;

  int m_lo = wave << 10;
  const f16* kp = kh + (m_lo + pr) * 32 + g * 8;
  const f16* vp0 = vh + r * HW + m_lo + g * 8;
  const f16* vp1 = vp0 + 16 * HW;

  for (int it = 0; it < 32; ++it) {
    f16x8 ak0 = *(const f16x8*)(kp);
    f16x8 ak1 = *(const f16x8*)(kp + 128);
    f16x8 bv0 = *(const f16x8*)(vp0);
    f16x8 bv1 = *(const f16x8*)(vp1);
    kp += 1024;  // 32 keys * 32 d
    vp0 += 32;
    vp1 += 32;
    // scores: sX[j] = S[key m0+8g+j(+4)][q-row n_base+(16+)r]
    f32x4 sA0 = mfma16(ak0, bq0, zero);
    f32x4 sA1 = mfma16(ak1, bq0, zero);
    f32x4 sB0 = mfma16(ak0, bq1, zero);
    f32x4 sB1 = mfma16(ak1, bq1, zero);
    float pA[8], pB[8];
#pragma unroll
    for (int j = 0; j < 4; j++) {
      pA[j] = EXP2(sA0[j] - Ca);
      pA[4 + j] = EXP2(sA1[j] - Ca);
      pB[j] = EXP2(sB0[j] - Cb);
      pB[4 + j] = EXP2(sB1[j] - Cb);
    }
    La += ((pA[0] + pA[1]) + (pA[2] + pA[3])) +
          ((pA[4] + pA[5]) + (pA[6] + pA[7]));
    Lb += ((pB[0] + pB[1]) + (pB[2] + pB[3])) +
          ((pB[4] + pB[5]) + (pB[6] + pB[7]));
    f16x8 paA, paB;
#pragma unroll
    for (int j = 0; j < 8; j++) {
      paA[j] = (f16)pA[j];
      paB[j] = (f16)pB[j];
    }
    accA0 = mfma16(paA, bv0, accA0);
    accA1 = mfma16(paA, bv1, accA1);
    accB0 = mfma16(paB, bv0, accB0);
    accB1 = mfma16(paB, bv1, accB1);
  }
  // ---- per-wave partials -> LDS (all on the same fixed scale) ----
  La += __shfl_xor(La, 16);
  La += __shfl_xor(La, 32);
  Lb += __shfl_xor(Lb, 16);
  Lb += __shfl_xor(Lb, 32);
#pragma unroll
  for (int j = 0; j < 4; j++) {
    s_acc[wave][4 * g + j][r] = accA0[j];
    s_acc[wave][4 * g + j][16 + r] = accA1[j];
    s_acc[wave][16 + 4 * g + j][r] = accB0[j];
    s_acc[wave][16 + 4 * g + j][16 + r] = accB1[j];
  }
  if (lane < 16) {
    s_L[wave][r] = La;
    s_L[wave][16 + r] = Lb;
  }
  __syncthreads();
  // ---- combine the 4 key-quarters: plain sums, then O/L ----
  for (int idx = threadIdx.x; idx < 1024; idx += 256) {
    int row = idx >> 5, d = idx & 31;
    float O = (s_acc[0][row][d] + s_acc[1][row][d]) +
              (s_acc[2][row][d] + s_acc[3][row][d]);
    float L = (s_L[0][row] + s_L[1][row]) + (s_L[2][row] + s_L[3][row]);
    newx[(n_base + row) * NC + h * 32 + d] = (f16)(O / L);
  }
}

// ---------- GEMM2: out = relu(Wlin[256,256] * newx + b) + x ----------------
__global__ __launch_bounds__(256) void k_gemm_proj(
    const f16* __restrict__ w, const f16* __restrict__ nx,
    const float* __restrict__ bias, const float* __restrict__ x,
    float* __restrict__ out) {
  int bm = blockIdx.x >> 6;  // 4
  int bn = blockIdx.x & 63;  // 64
  int wave = threadIdx.x >> 6, lane = threadIdx.x & 63;
  int r = lane & 15, g = lane >> 4;
  int m_row = bm * 64 + wave * 16 + r;
  int n0 = bn * 64;
  f32x4 acc[4] = {};
  for (int kk = 0; kk < NC; kk += 32) {
    f16x8 a = *(const f16x8*)&w[m_row * NC + kk + g * 8];
#pragma unroll
    for (int nt = 0; nt < 4; nt++) {
      f16x8 b = *(const f16x8*)&nx[(n0 + nt * 16 + r) * NC + kk + g * 8];
      acc[nt] = mfma16(a, b, acc[nt]);
    }
  }
  int mbase = bm * 64 + wave * 16 + g * 4;
  float bj[4];
#pragma unroll
  for (int j = 0; j < 4; j++) bj[j] = bias[mbase + j];
#pragma unroll
  for (int nt = 0; nt < 4; nt++)
#pragma unroll
    for (int j = 0; j < 4; j++) {
      int m = mbase + j, n = n0 + nt * 16 + r;
      float v = fmaxf(acc[nt][j] + bj[j], 0.f) + x[m * HW + n];
      out[m * HW + n] = v;
    }
}

// ---------------------------------------------------------------------------
extern "C" void kernel_launch(void* const* d_in, const int* in_sizes, int n_in,
                              void* d_out, int out_size, void* d_ws,
                              size_t ws_size, hipStream_t stream) {
  const float* x = (const float*)d_in[0];
  const float* w_pw = (const float*)d_in[1];
  const float* b_pw = (const float*)d_in[2];
  const float* w_dw = (const float*)d_in[3];
  const float* b_dw = (const float*)d_in[4];
  const float* w_lin = (const float*)d_in[5];
  const float* b_lin = (const float*)d_in[6];
  float* out = (float*)d_out;

  char* ws = (char*)d_ws;
  f16* wpw_h = (f16*)(ws + 0);            // 768*256*2      = 393216
  f16* wlin_h = (f16*)(ws + 393216);      // 256*256*2      = 131072
  f16* xt = (f16*)(ws + 524288);          // 4096*256*2     = 2097152
  float* qkv = (float*)(ws + 2621440);    // 768*4096*4     = 12582912
  f16* q_nm = (f16*)(ws + 15204352);      // 8*4096*32*2    = 2097152
  f16* k_nm = (f16*)(ws + 17301504);      // 2097152
  f16* v_cm = (f16*)(ws + 19398656);      // 2097152
  f16* nx = (f16*)(ws + 21495808);        // 2097152
  float* q_bound = (float*)(ws + 23592960);  // 8*4096*4    = 131072
  int* kmax_bits = (int*)(ws + 23724032);    // 32 -> total 23724064 bytes

  k_prep_w<<<512, 256, 0, stream>>>(w_pw, w_lin, wpw_h, wlin_h, kmax_bits);
  k_transpose_x<<<1024, 256, 0, stream>>>(x, xt);
  k_gemm_qkv<<<768, 256, 0, stream>>>(wpw_h, xt, b_pw, qkv);
  k_dwconv<<<768, 256, 0, stream>>>(qkv, w_dw, b_dw, q_nm, k_nm, v_cm);
  k_norms<<<256, 256, 0, stream>>>(q_nm, k_nm, q_bound, kmax_bits);
  k_attn<<<1024, 256, 0, stream>>>(q_nm, k_nm, v_cm, q_bound, kmax_bits, nx);
  k_gemm_proj<<<256, 256, 0, stream>>>(wlin_h, nx, b_lin, x, out);
}